// Round 10
// baseline (1188.046 us; speedup 1.0000x reference)
//
#include <hip/hip_runtime.h>
#include <stdint.h>

typedef __attribute__((ext_vector_type(8))) short bf16x8;
typedef __attribute__((ext_vector_type(4))) float f32x4;

__device__ __forceinline__ float bf2f(unsigned short u) {
  union { unsigned int i; float f; } x; x.i = ((unsigned int)u) << 16; return x.f;
}
__device__ __forceinline__ unsigned short f2bf(float f) {
  union { float f; unsigned int i; } x; x.f = f;
  unsigned int i = x.i;
  return (unsigned short)((i + 0x7FFFu + ((i >> 16) & 1u)) >> 16);  // RNE
}
__device__ __forceinline__ float f16lo(unsigned int u) {
  union { unsigned short s; _Float16 h; } x; x.s = (unsigned short)(u & 0xFFFFu);
  return (float)x.h;
}
__device__ __forceinline__ float f16hi(unsigned int u) {
  union { unsigned short s; _Float16 h; } x; x.s = (unsigned short)(u >> 16);
  return (float)x.h;
}
__device__ __forceinline__ unsigned int packf16(float a, float b) {
  union { unsigned short s; _Float16 h; } x, y;
  x.h = (_Float16)a; y.h = (_Float16)b;
  return (unsigned int)x.s | ((unsigned int)y.s << 16);
}
__device__ __forceinline__ unsigned int cvtpk_bf16(float lo, float hi) {
  unsigned int d;
  asm("v_cvt_pk_bf16_f32 %0, %1, %2" : "=v"(d) : "v"(lo), "v"(hi));
  return d;
}

// ---------------- CSR build ----------------

__global__ void count_kernel(const int* __restrict__ ei, int E, int* __restrict__ counts) {
  int e = blockIdx.x * blockDim.x + threadIdx.x;
  if (e < E) atomicAdd(&counts[ei[E + e]], 1);
}

__global__ void scan1_kernel(const int* __restrict__ counts, int n, int* __restrict__ bsum) {
  int i = blockIdx.x * 256 + threadIdx.x;
  int v = (i < n) ? counts[i] : 0;
  int lane = threadIdx.x & 63, w = threadIdx.x >> 6;
  for (int d = 32; d > 0; d >>= 1) v += __shfl_down(v, d, 64);
  __shared__ int ws[4];
  if (lane == 0) ws[w] = v;
  __syncthreads();
  if (threadIdx.x == 0) bsum[blockIdx.x] = ws[0] + ws[1] + ws[2] + ws[3];
}

__global__ void scan2_kernel(int* __restrict__ bsum, int G) {
  int t = threadIdx.x;
  int c = (G + 511) >> 9;
  int lo = min(t * c, G), hi = min(lo + c, G);
  int s = 0;
  for (int i = lo; i < hi; ++i) s += bsum[i];
  int lane = t & 63, w = t >> 6;
  int incl = s;
  for (int d = 1; d < 64; d <<= 1) { int u = __shfl_up(incl, d, 64); if (lane >= d) incl += u; }
  __shared__ int wsum[8];
  if (lane == 63) wsum[w] = incl;
  __syncthreads();
  int wpre = 0;
  for (int i = 0; i < w; ++i) wpre += wsum[i];
  int excl = wpre + incl - s;
  for (int i = lo; i < hi; ++i) { int v = bsum[i]; bsum[i] = excl; excl += v; }
}

__global__ void scan3_kernel(const int* __restrict__ counts, int n, const int* __restrict__ bsum,
                             int* __restrict__ offsets, int* __restrict__ cursor, int total) {
  int i = blockIdx.x * 256 + threadIdx.x;
  int v = (i < n) ? counts[i] : 0;
  int lane = threadIdx.x & 63, w = threadIdx.x >> 6;
  int incl = v;
  for (int d = 1; d < 64; d <<= 1) { int u = __shfl_up(incl, d, 64); if (lane >= d) incl += u; }
  __shared__ int wsum[4];
  if (lane == 63) wsum[w] = incl;
  __syncthreads();
  int pre = bsum[blockIdx.x];
  for (int j = 0; j < w; ++j) pre += wsum[j];
  if (i < n) {
    int excl = pre + incl - v;
    offsets[i] = excl;
    cursor[i] = excl;
  }
  if (i == 0) offsets[n] = total;
}

// fill: 16B record per edge in CSR slot: {src<<7 | (dst&127), 3x packed fp16 basis}

__global__ void fill_kernel(const int* __restrict__ ei, const float* __restrict__ pseudo,
                            int E, int* __restrict__ cursor, uint4* __restrict__ recs) {
  int e = blockIdx.x * blockDim.x + threadIdx.x;
  if (e >= E) return;
  int d = ei[E + e];
  int s = ei[e];
  float2 uv = ((const float2*)pseudo)[e];
  float u = uv.x, v = uv.y;
  float b0 = 0.5f * u * u - u + 0.5f, b1 = -u * u + u + 0.5f, b2 = 0.5f * u * u;
  float c0 = 0.5f * v * v - v + 0.5f, c1 = -v * v + v + 0.5f, c2 = 0.5f * v * v;
  int p = atomicAdd(&cursor[d], 1);
  uint4 r;
  r.x = (((unsigned int)s) << 7) | ((unsigned int)d & 127u);
  r.y = packf16(b0, b1);
  r.z = packf16(b2, c0);
  r.w = packf16(c1, c2);
  recs[p] = r;
}

// -------- weight repack, TRANSPOSED: Wt[64 cols][640 k]; k 0..575 = W.flat, 576..639 = root

__global__ void wconv_kernel(const float* __restrict__ W, const float* __restrict__ root,
                             unsigned short* __restrict__ Wt) {
  int i = blockIdx.x * blockDim.x + threadIdx.x;
  if (i >= 640 * 64) return;
  int co = i / 640, r = i % 640;
  float v = (r < 576) ? W[r * 64 + co] : root[(r - 576) * 64 + co];
  Wt[i] = f2bf(v);
}

// -------- x -> bf16

__global__ void xconv_kernel(const float4* __restrict__ x4, ushort4* __restrict__ xh4, int n4) {
  int i = blockIdx.x * blockDim.x + threadIdx.x;
  if (i < n4) {
    float4 v = x4[i];
    ushort4 o;
    o.x = f2bf(v.x); o.y = f2bf(v.y); o.z = f2bf(v.z); o.w = f2bf(v.w);
    xh4[i] = o;
  }
}

// ---------------- fused agg + GEMM ----------------
// Block 512 = 8 waves, 16 nodes. Phase B: block edge slice split into 8 EQUAL
// contiguous chunks (node-agnostic). Flat per-wave loop, 4-edge groups with
// 1-group lookahead; per-lane f32 accumulators; flush on (uniform) dst change
// via ds_add_f32 atomics into sAf[16][644] f32. Phase C: MFMA from sAf via
// v_cvt_pk_bf16_f32.

#define SAFROW 644
#define CAP 384

#define UNPACK_FMA(RY, RZ, RW, XV)                                 \
  {                                                                \
    float b0 = f16lo(RY), b1 = f16hi(RY), b2 = f16lo(RZ);          \
    float c0 = f16hi(RZ), c1 = f16lo(RW), c2 = f16hi(RW);          \
    float t0 = b0 * (XV), t1 = b1 * (XV), t2 = b2 * (XV);          \
    a0 += t0 * c0; a1 += t0 * c1; a2 += t0 * c2;                   \
    a3 += t1 * c0; a4 += t1 * c1; a5 += t1 * c2;                   \
    a6 += t2 * c0; a7 += t2 * c1; a8 += t2 * c2;                   \
  }

#define FLUSH(C)                                                             \
  {                                                                          \
    float* fb_ = &sAf[(C) * SAFROW + lane];                                  \
    atomicAdd(fb_ + 0,   a0); atomicAdd(fb_ + 64,  a1);                      \
    atomicAdd(fb_ + 128, a2); atomicAdd(fb_ + 192, a3);                      \
    atomicAdd(fb_ + 256, a4); atomicAdd(fb_ + 320, a5);                      \
    atomicAdd(fb_ + 384, a6); atomicAdd(fb_ + 448, a7);                      \
    atomicAdd(fb_ + 512, a8);                                                \
    a0 = a1 = a2 = a3 = a4 = a5 = a6 = a7 = a8 = 0.f;                        \
  }

#define LOADG(J, R0, R1, R2, R3, X0, X1, X2, X3)                             \
  {                                                                          \
    R0 = sRec[(J)]; R1 = sRec[(J) + 1]; R2 = sRec[(J) + 2]; R3 = sRec[(J) + 3]; \
    X0 = *(const unsigned short*)(Xb + (R0.x & 0xFFFFFF80u) + laneB);        \
    X1 = *(const unsigned short*)(Xb + (R1.x & 0xFFFFFF80u) + laneB);        \
    X2 = *(const unsigned short*)(Xb + (R2.x & 0xFFFFFF80u) + laneB);        \
    X3 = *(const unsigned short*)(Xb + (R3.x & 0xFFFFFF80u) + laneB);        \
  }

#define PROCG(R0, R1, R2, R3, X0, X1, X2, X3)                                \
  {                                                                          \
    int d0_ = __builtin_amdgcn_readfirstlane(R0.x) & 15;                     \
    int d1_ = __builtin_amdgcn_readfirstlane(R1.x) & 15;                     \
    int d2_ = __builtin_amdgcn_readfirstlane(R2.x) & 15;                     \
    int d3_ = __builtin_amdgcn_readfirstlane(R3.x) & 15;                     \
    if (d0_ == cur && d1_ == cur && d2_ == cur && d3_ == cur) {              \
      UNPACK_FMA(R0.y, R0.z, R0.w, bf2f(X0))                                 \
      UNPACK_FMA(R1.y, R1.z, R1.w, bf2f(X1))                                 \
      UNPACK_FMA(R2.y, R2.z, R2.w, bf2f(X2))                                 \
      UNPACK_FMA(R3.y, R3.z, R3.w, bf2f(X3))                                 \
    } else {                                                                 \
      if (d0_ != cur) { FLUSH(cur) cur = d0_; }                              \
      UNPACK_FMA(R0.y, R0.z, R0.w, bf2f(X0))                                 \
      if (d1_ != cur) { FLUSH(cur) cur = d1_; }                              \
      UNPACK_FMA(R1.y, R1.z, R1.w, bf2f(X1))                                 \
      if (d2_ != cur) { FLUSH(cur) cur = d2_; }                              \
      UNPACK_FMA(R2.y, R2.z, R2.w, bf2f(X2))                                 \
      if (d3_ != cur) { FLUSH(cur) cur = d3_; }                              \
      UNPACK_FMA(R3.y, R3.z, R3.w, bf2f(X3))                                 \
    }                                                                        \
  }

template <bool OUTBF16>
__global__ __launch_bounds__(512, 6) void fused_kernel(const int* __restrict__ offsets,
                                                       const uint4* __restrict__ recs,
                                                       const unsigned short* __restrict__ Xh,
                                                       const unsigned short* __restrict__ Wt,
                                                       const float* __restrict__ bias,
                                                       void* __restrict__ outv, int N) {
  __shared__ __align__(16) float sAf[16 * SAFROW];  // 41216 B
  __shared__ __align__(16) uint4 sRec[CAP];         //  6144 B
  int tid = threadIdx.x, w = tid >> 6, lane = tid & 63;
  int nodeBase = blockIdx.x * 16;
  int nTop = min(nodeBase + 16, N);
  const char* Xb = (const char*)Xh;
  unsigned int laneB = (unsigned int)lane * 2u;

  int blockBeg = offsets[nodeBase];
  int blockEnd = offsets[nTop];
  int stage = min(blockEnd - blockBeg, CAP);

  // ---- Phase A: stage records, zero agg area, write self rows
  for (int i = tid; i < stage; i += 512) sRec[i] = recs[(size_t)blockBeg + i];
  for (int i = tid; i < 16 * 144; i += 512) {
    int r = i / 144, c = i - r * 144;
    *(f32x4*)(&sAf[r * SAFROW + c * 4]) = (f32x4){0.f, 0.f, 0.f, 0.f};
  }
#pragma unroll
  for (int t = 0; t < 2; ++t) {
    int row = w * 2 + t;
    int n = nodeBase + row;
    if (n < nTop) sAf[row * SAFROW + 576 + lane] = bf2f(Xh[(size_t)n * 64 + lane]);
  }
  __syncthreads();

  // ---- Phase B: edge-balanced chunks
  {
    int chunk = (stage + 7) >> 3;
    int cBeg = w * chunk;
    int cEnd = min(stage, cBeg + chunk);
    if (cBeg < cEnd) {
      float a0 = 0.f, a1 = 0.f, a2 = 0.f, a3 = 0.f, a4 = 0.f,
            a5 = 0.f, a6 = 0.f, a7 = 0.f, a8 = 0.f;
      int cur = __builtin_amdgcn_readfirstlane(sRec[cBeg].x) & 15;
      int i = cBeg;
      int nfull = (cEnd - cBeg) >> 2;
      uint4 r0, r1, r2, r3, s0, s1, s2, s3;
      unsigned short px0, px1, px2, px3, py0, py1, py2, py3;
      if (nfull > 0) { LOADG(i, r0, r1, r2, r3, px0, px1, px2, px3) }
      int g = 0;
      while (g < nfull) {
        if (g + 1 < nfull) { LOADG(i + 4, s0, s1, s2, s3, py0, py1, py2, py3) }
        PROCG(r0, r1, r2, r3, px0, px1, px2, px3)
        i += 4; ++g;
        if (g >= nfull) break;
        if (g + 1 < nfull) { LOADG(i + 4, r0, r1, r2, r3, px0, px1, px2, px3) }
        PROCG(s0, s1, s2, s3, py0, py1, py2, py3)
        i += 4; ++g;
      }
      for (; i < cEnd; ++i) {  // <=3 tail edges
        uint4 rr = sRec[i];
        unsigned short xv = *(const unsigned short*)(Xb + (rr.x & 0xFFFFFF80u) + laneB);
        int dd = __builtin_amdgcn_readfirstlane(rr.x) & 15;
        if (dd != cur) { FLUSH(cur) cur = dd; }
        UNPACK_FMA(rr.y, rr.z, rr.w, bf2f(xv))
      }
      FLUSH(cur)
    }
    // overflow beyond CAP (rare): per-node by owner wave, global records
    if (blockEnd - blockBeg > CAP) {
      int gcap = blockBeg + CAP;
#pragma unroll
      for (int t = 0; t < 2; ++t) {
        int row = w * 2 + t;
        int n = nodeBase + row;
        if (n < nTop) {
          int beg = __builtin_amdgcn_readfirstlane(offsets[n]);
          int end = __builtin_amdgcn_readfirstlane(offsets[n + 1]);
          int s = beg > gcap ? beg : gcap;
          if (s < end) {
            float a0 = 0.f, a1 = 0.f, a2 = 0.f, a3 = 0.f, a4 = 0.f,
                  a5 = 0.f, a6 = 0.f, a7 = 0.f, a8 = 0.f;
            for (int j = s; j < end; ++j) {
              uint4 rr = recs[j];
              unsigned short xv = *(const unsigned short*)(Xb + (rr.x & 0xFFFFFF80u) + laneB);
              UNPACK_FMA(rr.y, rr.z, rr.w, bf2f(xv))
            }
            FLUSH(row)
          }
        }
      }
    }
  }
  __syncthreads();

  // ---- Phase C: GEMM (waves 0..3): 16 block-nodes x 16 cols each, K=640
  if (w < 4) {
    int r15 = lane & 15, kg = lane >> 4;
    f32x4 acc = {0.f, 0.f, 0.f, 0.f};
#pragma unroll
    for (int kk = 0; kk < 20; ++kk) {
      int kbase = kk * 32 + kg * 8;
      f32x4 v0 = *(const f32x4*)(&sAf[r15 * SAFROW + kbase]);
      f32x4 v1 = *(const f32x4*)(&sAf[r15 * SAFROW + kbase + 4]);
      union { unsigned int u[4]; bf16x8 v8; } af;
      af.u[0] = cvtpk_bf16(v0[0], v0[1]);
      af.u[1] = cvtpk_bf16(v0[2], v0[3]);
      af.u[2] = cvtpk_bf16(v1[0], v1[1]);
      af.u[3] = cvtpk_bf16(v1[2], v1[3]);
      bf16x8 bfr = *(const bf16x8*)(Wt + (size_t)(w * 16 + r15) * 640 + kbase);
      acc = __builtin_amdgcn_mfma_f32_16x16x32_bf16(af.v8, bfr, acc, 0, 0, 0);
    }
    // C/D: col = lane&15, row = (lane>>4)*4 + reg
    int col = w * 16 + r15;
    float bv = bias[col];
    int row0 = kg * 4;
#pragma unroll
    for (int r = 0; r < 4; ++r) {
      int node = nodeBase + row0 + r;
      if (node < N) {
        float val = fmaxf(acc[r] + bv, 0.f);
        size_t idx = (size_t)node * 64 + col;
        if (OUTBF16) ((unsigned short*)outv)[idx] = f2bf(val);
        else ((float*)outv)[idx] = val;
      }
    }
  }
}

// ---------------- host ----------------

extern "C" void kernel_launch(void* const* d_in, const int* in_sizes, int n_in,
                              void* d_out, int out_size, void* d_ws, size_t ws_size,
                              hipStream_t stream) {
  const float* x = (const float*)d_in[0];
  const int* ei = (const int*)d_in[1];
  const float* pseudo = (const float*)d_in[2];
  const float* W1 = (const float*)d_in[3];
  const float* root1 = (const float*)d_in[4];
  const float* b1 = (const float*)d_in[5];
  const float* W2 = (const float*)d_in[6];
  const float* root2 = (const float*)d_in[7];
  const float* b2 = (const float*)d_in[8];

  const int N = in_sizes[0] / 64;
  const int E = in_sizes[1] / 2;
  const int G = (N + 255) / 256;

  char* p = (char*)d_ws;
  auto carve = [&](size_t bytes) -> void* {
    void* r = (void*)p;
    p += (bytes + 255) & ~(size_t)255;
    return r;
  };
  int* counts = (int*)carve((size_t)N * 4);
  int* offsets = (int*)carve((size_t)(N + 1) * 4);
  int* cursor = (int*)carve((size_t)N * 4);
  int* bsum = (int*)carve((size_t)G * 4);
  uint4* recs = (uint4*)carve((size_t)E * 16);
  unsigned short* Wt1 = (unsigned short*)carve(640 * 64 * 2);
  unsigned short* Wt2 = (unsigned short*)carve(640 * 64 * 2);
  unsigned short* h = (unsigned short*)carve((size_t)N * 64 * 2);
  unsigned short* xh = (unsigned short*)carve((size_t)N * 64 * 2);
  (void)ws_size;

  hipMemsetAsync(counts, 0, (size_t)N * 4, stream);
  count_kernel<<<(E + 255) / 256, 256, 0, stream>>>(ei, E, counts);
  scan1_kernel<<<G, 256, 0, stream>>>(counts, N, bsum);
  scan2_kernel<<<1, 512, 0, stream>>>(bsum, G);
  scan3_kernel<<<G, 256, 0, stream>>>(counts, N, bsum, offsets, cursor, E);
  fill_kernel<<<(E + 255) / 256, 256, 0, stream>>>(ei, pseudo, E, cursor, recs);
  wconv_kernel<<<160, 256, 0, stream>>>(W1, root1, Wt1);
  wconv_kernel<<<160, 256, 0, stream>>>(W2, root2, Wt2);
  xconv_kernel<<<(N * 16 + 255) / 256, 256, 0, stream>>>((const float4*)x, (ushort4*)xh, N * 16);

  int FB = (N + 15) / 16;
  // layer 1: xh (bf16) -> h (bf16)
  fused_kernel<true><<<FB, 512, 0, stream>>>(offsets, recs, xh, Wt1, b1, (void*)h, N);
  // layer 2: h (bf16) -> d_out (fp32)
  fused_kernel<false><<<FB, 512, 0, stream>>>(offsets, recs, h, Wt2, b2, d_out, N);
}

// Round 11
// 460.619 us; speedup vs baseline: 2.5792x; 2.5792x over previous
//
#include <hip/hip_runtime.h>
#include <stdint.h>

typedef __attribute__((ext_vector_type(8))) short bf16x8;
typedef __attribute__((ext_vector_type(4))) float f32x4;

__device__ __forceinline__ float bf2f(unsigned short u) {
  union { unsigned int i; float f; } x; x.i = ((unsigned int)u) << 16; return x.f;
}
__device__ __forceinline__ unsigned short f2bf(float f) {
  union { float f; unsigned int i; } x; x.f = f;
  unsigned int i = x.i;
  return (unsigned short)((i + 0x7FFFu + ((i >> 16) & 1u)) >> 16);  // RNE
}
__device__ __forceinline__ float f16lo(unsigned int u) {
  union { unsigned short s; _Float16 h; } x; x.s = (unsigned short)(u & 0xFFFFu);
  return (float)x.h;
}
__device__ __forceinline__ float f16hi(unsigned int u) {
  union { unsigned short s; _Float16 h; } x; x.s = (unsigned short)(u >> 16);
  return (float)x.h;
}
__device__ __forceinline__ unsigned int packf16(float a, float b) {
  union { unsigned short s; _Float16 h; } x, y;
  x.h = (_Float16)a; y.h = (_Float16)b;
  return (unsigned int)x.s | ((unsigned int)y.s << 16);
}

// ---------------- CSR build ----------------

__global__ void count_kernel(const int* __restrict__ ei, int E, int* __restrict__ counts) {
  int e = blockIdx.x * blockDim.x + threadIdx.x;
  if (e < E) atomicAdd(&counts[ei[E + e]], 1);
}

__global__ void scan1_kernel(const int* __restrict__ counts, int n, int* __restrict__ bsum) {
  int i = blockIdx.x * 256 + threadIdx.x;
  int v = (i < n) ? counts[i] : 0;
  int lane = threadIdx.x & 63, w = threadIdx.x >> 6;
  for (int d = 32; d > 0; d >>= 1) v += __shfl_down(v, d, 64);
  __shared__ int ws[4];
  if (lane == 0) ws[w] = v;
  __syncthreads();
  if (threadIdx.x == 0) bsum[blockIdx.x] = ws[0] + ws[1] + ws[2] + ws[3];
}

__global__ void scan2_kernel(int* __restrict__ bsum, int G) {
  int t = threadIdx.x;
  int c = (G + 511) >> 9;
  int lo = min(t * c, G), hi = min(lo + c, G);
  int s = 0;
  for (int i = lo; i < hi; ++i) s += bsum[i];
  int lane = t & 63, w = t >> 6;
  int incl = s;
  for (int d = 1; d < 64; d <<= 1) { int u = __shfl_up(incl, d, 64); if (lane >= d) incl += u; }
  __shared__ int wsum[8];
  if (lane == 63) wsum[w] = incl;
  __syncthreads();
  int wpre = 0;
  for (int i = 0; i < w; ++i) wpre += wsum[i];
  int excl = wpre + incl - s;
  for (int i = lo; i < hi; ++i) { int v = bsum[i]; bsum[i] = excl; excl += v; }
}

__global__ void scan3_kernel(const int* __restrict__ counts, int n, const int* __restrict__ bsum,
                             int* __restrict__ offsets, int* __restrict__ cursor, int total) {
  int i = blockIdx.x * 256 + threadIdx.x;
  int v = (i < n) ? counts[i] : 0;
  int lane = threadIdx.x & 63, w = threadIdx.x >> 6;
  int incl = v;
  for (int d = 1; d < 64; d <<= 1) { int u = __shfl_up(incl, d, 64); if (lane >= d) incl += u; }
  __shared__ int wsum[4];
  if (lane == 63) wsum[w] = incl;
  __syncthreads();
  int pre = bsum[blockIdx.x];
  for (int j = 0; j < w; ++j) pre += wsum[j];
  if (i < n) {
    int excl = pre + incl - v;
    offsets[i] = excl;
    cursor[i] = excl;
  }
  if (i == 0) offsets[n] = total;
}

// fill: 16B record per edge in CSR slot: {src<<7 | (dst&127), 3x packed fp16 basis}

__global__ void fill_kernel(const int* __restrict__ ei, const float* __restrict__ pseudo,
                            int E, int* __restrict__ cursor, uint4* __restrict__ recs) {
  int e = blockIdx.x * blockDim.x + threadIdx.x;
  if (e >= E) return;
  int d = ei[E + e];
  int s = ei[e];
  float2 uv = ((const float2*)pseudo)[e];
  float u = uv.x, v = uv.y;
  float b0 = 0.5f * u * u - u + 0.5f, b1 = -u * u + u + 0.5f, b2 = 0.5f * u * u;
  float c0 = 0.5f * v * v - v + 0.5f, c1 = -v * v + v + 0.5f, c2 = 0.5f * v * v;
  int p = atomicAdd(&cursor[d], 1);
  uint4 r;
  r.x = (((unsigned int)s) << 7) | ((unsigned int)d & 127u);
  r.y = packf16(b0, b1);
  r.z = packf16(b2, c0);
  r.w = packf16(c1, c2);
  recs[p] = r;
}

// -------- weight repack, TRANSPOSED: Wt[64 cols][640 k]; k 0..575 = W.flat, 576..639 = root

__global__ void wconv_kernel(const float* __restrict__ W, const float* __restrict__ root,
                             unsigned short* __restrict__ Wt) {
  int i = blockIdx.x * blockDim.x + threadIdx.x;
  if (i >= 640 * 64) return;
  int co = i / 640, r = i % 640;
  float v = (r < 576) ? W[r * 64 + co] : root[(r - 576) * 64 + co];
  Wt[i] = f2bf(v);
}

// -------- x -> bf16

__global__ void xconv_kernel(const float4* __restrict__ x4, ushort4* __restrict__ xh4, int n4) {
  int i = blockIdx.x * blockDim.x + threadIdx.x;
  if (i < n4) {
    float4 v = x4[i];
    ushort4 o;
    o.x = f2bf(v.x); o.y = f2bf(v.y); o.z = f2bf(v.z); o.w = f2bf(v.w);
    xh4[i] = o;
  }
}

// ---------------- fused agg + GEMM ----------------
// Block 256 = 4 waves, 16 nodes. Phase B: each wave runs ONE flat contiguous
// CSR stream over its 4 nodes (no per-node pipeline restart). 3-slot rotating
// record prefetch (rec j+3 in flight), gathers issued 2 edges ahead. Node
// boundary detected via uniform readfirstlane(rec.x)&15 change -> plain LDS
// flush (wave owns its rows; no atomics). Phase C: 16x64 MFMA tile.

#define SROW 648

#define GX(R) (*(const unsigned short*)(Xb + ((R).x & 0xFFFFFF80u) + laneB))

#define FLUSHROW(C)                                                \
  {                                                                \
    int rb_ = (C) * SROW + lane;                                   \
    sA[rb_ + 0 * 64] = (short)f2bf(a0);                            \
    sA[rb_ + 1 * 64] = (short)f2bf(a1);                            \
    sA[rb_ + 2 * 64] = (short)f2bf(a2);                            \
    sA[rb_ + 3 * 64] = (short)f2bf(a3);                            \
    sA[rb_ + 4 * 64] = (short)f2bf(a4);                            \
    sA[rb_ + 5 * 64] = (short)f2bf(a5);                            \
    sA[rb_ + 6 * 64] = (short)f2bf(a6);                            \
    sA[rb_ + 7 * 64] = (short)f2bf(a7);                            \
    sA[rb_ + 8 * 64] = (short)f2bf(a8);                            \
    a0 = a1 = a2 = a3 = a4 = a5 = a6 = a7 = a8 = 0.f;              \
  }

#define PROC(R, XU)                                                \
  {                                                                \
    int d_ = __builtin_amdgcn_readfirstlane((R).x) & 15;           \
    if (d_ != cur) { FLUSHROW(cur) cur = d_; }                     \
    float xv = bf2f((unsigned short)(XU));                         \
    float b0 = f16lo((R).y), b1 = f16hi((R).y), b2 = f16lo((R).z); \
    float c0 = f16hi((R).z), c1 = f16lo((R).w), c2 = f16hi((R).w); \
    float t0 = b0 * xv, t1 = b1 * xv, t2 = b2 * xv;                \
    a0 += t0 * c0; a1 += t0 * c1; a2 += t0 * c2;                   \
    a3 += t1 * c0; a4 += t1 * c1; a5 += t1 * c2;                   \
    a6 += t2 * c0; a7 += t2 * c1; a8 += t2 * c2;                   \
  }

template <bool OUTBF16>
__global__ __launch_bounds__(256) void fused_kernel(const int* __restrict__ offsets,
                                                    const uint4* __restrict__ recs,
                                                    const unsigned short* __restrict__ Xh,
                                                    const unsigned short* __restrict__ Wt,
                                                    const float* __restrict__ bias,
                                                    void* __restrict__ outv, int N) {
  __shared__ __align__(16) short sA[16 * SROW];  // 20736 B
  int tid = threadIdx.x, w = tid >> 6, lane = tid & 63;
  int nodeBase = blockIdx.x * 16;
  const char* Xb = (const char*)Xh;
  unsigned int laneB = (unsigned int)lane * 2u;

  // ---- Phase A: zero agg slots (rows x 576 shorts), write self rows
  {
    f32x4 z = {0.f, 0.f, 0.f, 0.f};
    for (int i = tid; i < 16 * 36; i += 256) {
      int r = i / 36, c = i - r * 36;
      *(f32x4*)((char*)sA + r * (SROW * 2) + c * 16) = z;
    }
  }
#pragma unroll
  for (int t = 0; t < 4; ++t) {
    int row = w * 4 + t;
    int n = nodeBase + row;
    if (n < N) sA[row * SROW + 576 + lane] = (short)Xh[(size_t)n * 64 + lane];
  }

  // ---- Phase B: flat per-wave stream over nodes w*4 .. w*4+3
  {
    int n0 = nodeBase + w * 4;
    int n1 = min(n0 + 4, N);
    if (n0 < N) {
      int j = __builtin_amdgcn_readfirstlane(offsets[n0]);
      int jEnd = __builtin_amdgcn_readfirstlane(offsets[n1]);
      if (j < jEnd) {
        int last = jEnd - 1;
        float a0 = 0.f, a1 = 0.f, a2 = 0.f, a3 = 0.f, a4 = 0.f,
              a5 = 0.f, a6 = 0.f, a7 = 0.f, a8 = 0.f;
        uint4 rA = recs[j];
        uint4 rB = recs[min(j + 1, last)];
        uint4 rC = recs[min(j + 2, last)];
        unsigned int xA = GX(rA);
        unsigned int xB = GX(rB);
        unsigned int xC;
        int cur = __builtin_amdgcn_readfirstlane(rA.x) & 15;
        for (;;) {
          // phase 0: edge j  (uses rA,xA); prefetch rec j+3 -> rA, gather rec j+2 -> xC
          {
            uint4 rN = recs[min(j + 3, last)];
            xC = GX(rC);
            PROC(rA, xA)
            rA = rN;
            if (++j >= jEnd) break;
          }
          // phase 1: edge j (uses rB,xB); prefetch -> rB, gather rA(rec j+2) -> xA
          {
            uint4 rN = recs[min(j + 3, last)];
            xA = GX(rA);
            PROC(rB, xB)
            rB = rN;
            if (++j >= jEnd) break;
          }
          // phase 2: edge j (uses rC,xC); prefetch -> rC, gather rB(rec j+2) -> xB
          {
            uint4 rN = recs[min(j + 3, last)];
            xB = GX(rB);
            PROC(rC, xC)
            rC = rN;
            if (++j >= jEnd) break;
          }
        }
        FLUSHROW(cur)
      }
    }
  }
  __syncthreads();

  // ---- Phase C: GEMM: 16 block-nodes x 16 cols per wave, K=640
  {
    int r15 = lane & 15, kg = lane >> 4;
    f32x4 acc = {0.f, 0.f, 0.f, 0.f};
#pragma unroll
    for (int kk = 0; kk < 20; ++kk) {
      int kbase = kk * 32 + kg * 8;
      bf16x8 af = *(const bf16x8*)(&sA[r15 * SROW + kbase]);
      bf16x8 bfr = *(const bf16x8*)(Wt + (size_t)(w * 16 + r15) * 640 + kbase);
      acc = __builtin_amdgcn_mfma_f32_16x16x32_bf16(af, bfr, acc, 0, 0, 0);
    }
    // C/D: col = lane&15, row = (lane>>4)*4 + reg
    int col = w * 16 + r15;
    float bv = bias[col];
    int row0 = kg * 4;
#pragma unroll
    for (int r = 0; r < 4; ++r) {
      int node = nodeBase + row0 + r;
      if (node < N) {
        float val = fmaxf(acc[r] + bv, 0.f);
        size_t idx = (size_t)node * 64 + col;
        if (OUTBF16) ((unsigned short*)outv)[idx] = f2bf(val);
        else ((float*)outv)[idx] = val;
      }
    }
  }
}

// ---------------- host ----------------

extern "C" void kernel_launch(void* const* d_in, const int* in_sizes, int n_in,
                              void* d_out, int out_size, void* d_ws, size_t ws_size,
                              hipStream_t stream) {
  const float* x = (const float*)d_in[0];
  const int* ei = (const int*)d_in[1];
  const float* pseudo = (const float*)d_in[2];
  const float* W1 = (const float*)d_in[3];
  const float* root1 = (const float*)d_in[4];
  const float* b1 = (const float*)d_in[5];
  const float* W2 = (const float*)d_in[6];
  const float* root2 = (const float*)d_in[7];
  const float* b2 = (const float*)d_in[8];

  const int N = in_sizes[0] / 64;
  const int E = in_sizes[1] / 2;
  const int G = (N + 255) / 256;

  char* p = (char*)d_ws;
  auto carve = [&](size_t bytes) -> void* {
    void* r = (void*)p;
    p += (bytes + 255) & ~(size_t)255;
    return r;
  };
  int* counts = (int*)carve((size_t)N * 4);
  int* offsets = (int*)carve((size_t)(N + 1) * 4);
  int* cursor = (int*)carve((size_t)N * 4);
  int* bsum = (int*)carve((size_t)G * 4);
  uint4* recs = (uint4*)carve((size_t)E * 16);
  unsigned short* Wt1 = (unsigned short*)carve(640 * 64 * 2);
  unsigned short* Wt2 = (unsigned short*)carve(640 * 64 * 2);
  unsigned short* h = (unsigned short*)carve((size_t)N * 64 * 2);
  unsigned short* xh = (unsigned short*)carve((size_t)N * 64 * 2);
  (void)ws_size;

  hipMemsetAsync(counts, 0, (size_t)N * 4, stream);
  count_kernel<<<(E + 255) / 256, 256, 0, stream>>>(ei, E, counts);
  scan1_kernel<<<G, 256, 0, stream>>>(counts, N, bsum);
  scan2_kernel<<<1, 512, 0, stream>>>(bsum, G);
  scan3_kernel<<<G, 256, 0, stream>>>(counts, N, bsum, offsets, cursor, E);
  fill_kernel<<<(E + 255) / 256, 256, 0, stream>>>(ei, pseudo, E, cursor, recs);
  wconv_kernel<<<160, 256, 0, stream>>>(W1, root1, Wt1);
  wconv_kernel<<<160, 256, 0, stream>>>(W2, root2, Wt2);
  xconv_kernel<<<(N * 16 + 255) / 256, 256, 0, stream>>>((const float4*)x, (ushort4*)xh, N * 16);

  int FB = (N + 15) / 16;
  // layer 1: xh (bf16) -> h (bf16)
  fused_kernel<true><<<FB, 256, 0, stream>>>(offsets, recs, xh, Wt1, b1, (void*)h, N);
  // layer 2: h (bf16) -> d_out (fp32)
  fused_kernel<false><<<FB, 256, 0, stream>>>(offsets, recs, h, Wt2, b2, d_out, N);
}